// Round 1
// 145.002 us; speedup vs baseline: 1.0194x; 1.0194x over previous
//
#include <hip/hip_runtime.h>

// Problem constants (fixed by the dataset)
constexpr int S_  = 4096;
constexpr int B_  = 2;
constexpr int C_  = 256;
constexpr int H_  = 8;
constexpr int E_  = 131072;
constexpr int CC_ = 32;
constexpr int MR  = S_ * B_;   // 8192 rows for all GEMMs

typedef __attribute__((ext_vector_type(8))) short bf16x8_t;
typedef __attribute__((ext_vector_type(4))) float f32x4_t;

__device__ __forceinline__ unsigned short f2bf(float f) {
    unsigned int u = __float_as_uint(f);
    u += 0x7fffu + ((u >> 16) & 1u);   // round-to-nearest-even
    return (unsigned short)(u >> 16);
}
__device__ __forceinline__ float bflo(unsigned int u) { return __uint_as_float(u << 16); }
__device__ __forceinline__ float bfhi(unsigned int u) { return __uint_as_float(u & 0xffff0000u); }

__device__ __forceinline__ void cast8(const float* __restrict__ src, unsigned short* __restrict__ dst, int i) {
    const float4* s = (const float4*)src + (size_t)i * 2;
    float4 a = s[0], b = s[1];
    uint4 o;
    o.x = (unsigned)f2bf(a.x) | ((unsigned)f2bf(a.y) << 16);
    o.y = (unsigned)f2bf(a.z) | ((unsigned)f2bf(a.w) << 16);
    o.z = (unsigned)f2bf(b.x) | ((unsigned)f2bf(b.y) << 16);
    o.w = (unsigned)f2bf(b.z) | ((unsigned)f2bf(b.w) << 16);
    *((uint4*)dst + i) = o;
}

// ---------------- K1: histogram + casts ----------------
// blocks [0,512): hist; [512,1536): cast x; [1536,1664): cast W (4 matrices)

__global__ __launch_bounds__(256) void prep_kernel(
        const int* __restrict__ q_id, int* __restrict__ count,
        const float* __restrict__ x, unsigned short* __restrict__ xb,
        const float* __restrict__ Wq, const float* __restrict__ Wk,
        const float* __restrict__ Wv, const float* __restrict__ Wx,
        unsigned short* __restrict__ Wb) {
    const int bid = blockIdx.x, tid = threadIdx.x;
    if (bid < 512) {
        atomicAdd(&count[q_id[bid * 256 + tid]], 1);
    } else if (bid < 1536) {
        cast8(x, xb, (bid - 512) * 256 + tid);
    } else {
        int idx = bid - 1536;
        int z = idx >> 5;
        const float* src = (z == 0) ? Wq : (z == 1) ? Wk : (z == 2) ? Wv : Wx;
        cast8(src, Wb + (size_t)z * (C_ * C_), (idx & 31) * 256 + tid);
    }
}

// ---------------- K2: scan ----------------

__global__ __launch_bounds__(1024) void scan_kernel(const int* __restrict__ count,
                                                    int* __restrict__ base,
                                                    int* __restrict__ cursor) {
    __shared__ int wsums[16];
    const int t = threadIdx.x, lane = t & 63, w = t >> 6;
    int c0 = count[4 * t + 0], c1 = count[4 * t + 1];
    int c2 = count[4 * t + 2], c3 = count[4 * t + 3];
    int tsum = c0 + c1 + c2 + c3;
    int x = tsum;
#pragma unroll
    for (int off = 1; off < 64; off <<= 1) {
        int y = __shfl_up(x, off);
        if (lane >= off) x += y;
    }
    if (lane == 63) wsums[w] = x;
    __syncthreads();
    if (t == 0) {
        int run = 0;
#pragma unroll
        for (int i = 0; i < 16; ++i) { int v = wsums[i]; wsums[i] = run; run += v; }
        base[S_] = run;
    }
    __syncthreads();
    int excl = x - tsum + wsums[w];
    int b0 = excl, b1 = b0 + c0, b2 = b1 + c1, b3 = b2 + c2;
    base[4 * t + 0] = b0; base[4 * t + 1] = b1;
    base[4 * t + 2] = b2; base[4 * t + 3] = b3;
    cursor[4 * t + 0] = b0; cursor[4 * t + 1] = b1;
    cursor[4 * t + 2] = b2; cursor[4 * t + 3] = b3;
}

// ---------------- K3: scatter + QKV GEMM (A-tile reused for q,k,v) ----------------
// blocks [0,512): gemm — 4 n-blocks x 128 m-groups, one 64-row chunk each.
// Per wave: THREE B-strips 16x256 (Wq,Wk,Wv cols) in 96 VGPRs; each staged
// A-tile feeds 96 MFMA (3x fewer LDS stages / barriers / A re-reads than the
// 12-n-block layout). blocks [512,1024): scatter.

__global__ __launch_bounds__(256) void scatter_qkv_kernel(
        const int* __restrict__ q_id, const int* __restrict__ k_id,
        int* __restrict__ cursor, int* __restrict__ koff_sorted,
        const unsigned short* __restrict__ xb, const unsigned short* __restrict__ Wb,
        const float* __restrict__ bq, const float* __restrict__ bk, const float* __restrict__ bv,
        unsigned short* __restrict__ qb, unsigned short* __restrict__ kvb) {
    __shared__ __align__(16) unsigned short As[64][264];   // 33 KB, +8 pad
    const int bid = blockIdx.x, tid = threadIdx.x;
    if (bid >= 512) {
        int e = (bid - 512) * 256 + tid;
        int pos = atomicAdd(&cursor[q_id[e]], 1);
        koff_sorted[pos] = k_id[e] << 10;          // element offset into kvb
        return;
    }
    const int nb = bid & 3, mg = bid >> 2;         // n-block (64 cols), m-group
    const int lane = tid & 63, wave = tid >> 6;
    const int l16 = lane & 15, quad = lane >> 4;
    const int colz = (nb << 6) + (wave << 4);      // col within each matrix

    // Three B-strips: rows [colz, colz+16) of Wq, Wk, Wv — 96 VGPRs total
    bf16x8_t breg[3][8];
#pragma unroll
    for (int z = 0; z < 3; ++z) {
        const unsigned short* Wrow = Wb + (size_t)z * (C_ * C_) + (size_t)(colz + l16) * C_;
#pragma unroll
        for (int ks = 0; ks < 8; ++ks)
            breg[z][ks] = *(const bf16x8_t*)(Wrow + ks * 32 + quad * 8);
    }
    const float bc0 = bq[colz + l16];
    const float bc1 = bk[colz + l16];
    const float bc2 = bv[colz + l16];

    const int mbase = mg * 64;
#pragma unroll
    for (int it = 0; it < 8; ++it) {
        int l = it * 256 + tid;
        int r = l >> 5, cc = (l & 31) << 3;
        *(uint4*)&As[r][cc] = *(const uint4*)&xb[(size_t)(mbase + r) * C_ + cc];
    }
    __syncthreads();

#pragma unroll
    for (int mt = 0; mt < 4; ++mt) {
        bf16x8_t a[8];
#pragma unroll
        for (int ks = 0; ks < 8; ++ks)
            a[ks] = *(const bf16x8_t*)&As[mt * 16 + l16][ks * 32 + quad * 8];
        const int row0 = mbase + mt * 16 + quad * 4;
        // z = 0: q
        {
            f32x4_t acc = {0.f, 0.f, 0.f, 0.f};
#pragma unroll
            for (int ks = 0; ks < 8; ++ks)
                acc = __builtin_amdgcn_mfma_f32_16x16x32_bf16(a[ks], breg[0][ks], acc, 0, 0, 0);
#pragma unroll
            for (int r = 0; r < 4; ++r)
                qb[(size_t)(row0 + r) * 256 + colz + l16] = f2bf(acc[r] + bc0);
        }
        // z = 1: k  (kvb cols [0,256))
        {
            f32x4_t acc = {0.f, 0.f, 0.f, 0.f};
#pragma unroll
            for (int ks = 0; ks < 8; ++ks)
                acc = __builtin_amdgcn_mfma_f32_16x16x32_bf16(a[ks], breg[1][ks], acc, 0, 0, 0);
#pragma unroll
            for (int r = 0; r < 4; ++r)
                kvb[(size_t)(row0 + r) * 512 + colz + l16] = f2bf(acc[r] + bc1);
        }
        // z = 2: v  (kvb cols [256,512))
        {
            f32x4_t acc = {0.f, 0.f, 0.f, 0.f};
#pragma unroll
            for (int ks = 0; ks < 8; ++ks)
                acc = __builtin_amdgcn_mfma_f32_16x16x32_bf16(a[ks], breg[2][ks], acc, 0, 0, 0);
#pragma unroll
            for (int r = 0; r < 4; ++r)
                kvb[(size_t)(row0 + r) * 512 + 256 + colz + l16] = f2bf(acc[r] + bc2);
        }
    }
}

// ---------------- K4: edge attention (4-deep gather pipeline) ----------------

__global__ __launch_bounds__(256) void attn_edge(
        const unsigned short* __restrict__ qb, const unsigned short* __restrict__ kvb,
        const int* __restrict__ base, const int* __restrict__ koff,
        unsigned short* __restrict__ attnb) {
    __shared__ float red[2][64][9];
    const int lane = threadIdx.x & 63;
    const int wave = threadIdx.x >> 6;
    const int rw = wave >> 1, part = wave & 1;
    const int s = blockIdx.x * 2 + rw;
    const int half = lane >> 5, hl = lane & 31;
    const int e0 = __builtin_amdgcn_readfirstlane(base[s]);
    const int e1 = __builtin_amdgcn_readfirstlane(base[s + 1]);

    const uint4 qq = *((const uint4*)(qb + (size_t)(s * 2 + half) * C_) + hl);
    const float q0 = bflo(qq.x), q1 = bfhi(qq.x), q2 = bflo(qq.y), q3 = bfhi(qq.y);
    const float q4 = bflo(qq.z), q5 = bfhi(qq.z), q6 = bflo(qq.w), q7 = bfhi(qq.w);

    float a0 = 0.f, a1 = 0.f, a2 = 0.f, a3 = 0.f, a4 = 0.f, a5 = 0.f, a6 = 0.f, a7 = 0.f;
    float wsum = 0.f;
    const float scale = 0.17677669529663687f;   // 1/sqrt(32)

    auto edge = [&](const uint4& kk, const uint4& vv) {
        float p = q0 * bflo(kk.x) + q1 * bfhi(kk.x)
                + q2 * bflo(kk.y) + q3 * bfhi(kk.y)
                + q4 * bflo(kk.z) + q5 * bfhi(kk.z)
                + q6 * bflo(kk.w) + q7 * bfhi(kk.w);
        p += __shfl_xor(p, 1);
        p += __shfl_xor(p, 2);
        const float w = __expf(p * scale);
        a0 = fmaf(w, bflo(vv.x), a0); a1 = fmaf(w, bfhi(vv.x), a1);
        a2 = fmaf(w, bflo(vv.y), a2); a3 = fmaf(w, bfhi(vv.y), a3);
        a4 = fmaf(w, bflo(vv.z), a4); a5 = fmaf(w, bfhi(vv.z), a5);
        a6 = fmaf(w, bflo(vv.w), a6); a7 = fmaf(w, bfhi(vv.w), a7);
        wsum += w;
    };
    auto fetch = [&](int my, int t, uint4& kk, uint4& vv) {
        int o = __builtin_amdgcn_readlane(my, part + 2 * t);
        const uint4* p = (const uint4*)(kvb + o + half * 512);
        kk = p[hl]; vv = p[32 + hl];
    };

    for (int b0 = e0; b0 < e1; b0 += 64) {
        const int m = min(64, e1 - b0);
        const int my = koff[b0 + ((lane < m) ? lane : 0)];
        const int nm = (m > part) ? ((m - part + 1) >> 1) : 0;
        uint4 k0 = {}, v0 = {}, k1 = {}, v1 = {};
        uint4 k2 = {}, v2 = {}, k3 = {}, v3 = {};
        if (nm > 0) fetch(my, 0, k0, v0);
        if (nm > 1) fetch(my, 1, k1, v1);
        if (nm > 2) fetch(my, 2, k2, v2);
        if (nm > 3) fetch(my, 3, k3, v3);
        int t = 0;
        for (; t + 7 < nm; t += 4) {
            edge(k0, v0); fetch(my, t + 4, k0, v0);
            edge(k1, v1); fetch(my, t + 5, k1, v1);
            edge(k2, v2); fetch(my, t + 6, k2, v2);
            edge(k3, v3); fetch(my, t + 7, k3, v3);
        }
        const int rem = nm - t;   // 0..7
        if (rem > 0) { edge(k0, v0); if (rem > 4) fetch(my, t + 4, k0, v0); }
        if (rem > 1) { edge(k1, v1); if (rem > 5) fetch(my, t + 5, k1, v1); }
        if (rem > 2) { edge(k2, v2); if (rem > 6) fetch(my, t + 6, k2, v2); }
        if (rem > 3) edge(k3, v3);
        if (rem > 4) edge(k0, v0);
        if (rem > 5) edge(k1, v1);
        if (rem > 6) edge(k2, v2);
    }

    if (part == 1) {
        float* r = red[rw][lane];
        r[0] = a0; r[1] = a1; r[2] = a2; r[3] = a3;
        r[4] = a4; r[5] = a5; r[6] = a6; r[7] = a7; r[8] = wsum;
    }
    __syncthreads();
    if (part == 0) {
        const float* r = red[rw][lane];
        a0 += r[0]; a1 += r[1]; a2 += r[2]; a3 += r[3];
        a4 += r[4]; a5 += r[5]; a6 += r[6]; a7 += r[7]; wsum += r[8];
        const float inv = 1.0f / wsum;
        uint4 o;
        o.x = (unsigned)f2bf(a0 * inv) | ((unsigned)f2bf(a1 * inv) << 16);
        o.y = (unsigned)f2bf(a2 * inv) | ((unsigned)f2bf(a3 * inv) << 16);
        o.z = (unsigned)f2bf(a4 * inv) | ((unsigned)f2bf(a5 * inv) << 16);
        o.w = (unsigned)f2bf(a6 * inv) | ((unsigned)f2bf(a7 * inv) << 16);
        *((uint4*)(attnb + (size_t)(s * 2 + half) * C_) + hl) = o;
    }
}

// ---------------- K5: output projection (weights-in-registers) ----------------
// 512 blocks = 4 n-blocks x 128 m-groups (one 64-row chunk each). fp32 out.

__global__ __launch_bounds__(256) void gemm_proj(
        const unsigned short* __restrict__ attnb, const unsigned short* __restrict__ Wxb,
        const float* __restrict__ bx, float* __restrict__ out) {
    __shared__ __align__(16) unsigned short As[64][264];
    const int tid = threadIdx.x;
    const int nb = blockIdx.x & 3, mg = blockIdx.x >> 2;
    const int lane = tid & 63, wave = tid >> 6;
    const int l16 = lane & 15, quad = lane >> 4;
    const int colz = (nb << 6) + (wave << 4);

    const unsigned short* Wrow = Wxb + (size_t)(colz + l16) * C_;
    bf16x8_t breg[8];
#pragma unroll
    for (int ks = 0; ks < 8; ++ks)
        breg[ks] = *(const bf16x8_t*)(Wrow + ks * 32 + quad * 8);
    const float bcol = bx[colz + l16];
    const int ocol = colz + l16;

    const int mbase = mg * 64;
#pragma unroll
    for (int it = 0; it < 8; ++it) {
        int l = it * 256 + tid;
        int r = l >> 5, cc = (l & 31) << 3;
        *(uint4*)&As[r][cc] = *(const uint4*)&attnb[(size_t)(mbase + r) * C_ + cc];
    }
    __syncthreads();
#pragma unroll
    for (int mt = 0; mt < 4; ++mt) {
        f32x4_t acc = {0.f, 0.f, 0.f, 0.f};
#pragma unroll
        for (int ks = 0; ks < 8; ++ks) {
            bf16x8_t a = *(const bf16x8_t*)&As[mt * 16 + l16][ks * 32 + quad * 8];
            acc = __builtin_amdgcn_mfma_f32_16x16x32_bf16(a, breg[ks], acc, 0, 0, 0);
        }
        const int row0 = mbase + mt * 16 + quad * 4;
#pragma unroll
        for (int r = 0; r < 4; ++r)
            out[(size_t)(row0 + r) * C_ + ocol] = acc[r] + bcol;
    }
}

// ---------------- launch ----------------

extern "C" void kernel_launch(void* const* d_in, const int* in_sizes, int n_in,
                              void* d_out, int out_size, void* d_ws, size_t ws_size,
                              hipStream_t stream) {
    const float* x  = (const float*)d_in[0];
    const int* q_id = (const int*)d_in[1];
    const int* k_id = (const int*)d_in[2];
    const float* Wq = (const float*)d_in[3];
    const float* bq = (const float*)d_in[4];
    const float* Wk = (const float*)d_in[5];
    const float* bk = (const float*)d_in[6];
    const float* Wv = (const float*)d_in[7];
    const float* bv = (const float*)d_in[8];
    const float* Wx = (const float*)d_in[9];
    const float* bx = (const float*)d_in[10];
    float* out = (float*)d_out;

    char* ws = (char*)d_ws;
    unsigned short* xb    = (unsigned short*)ws;                 ws += (size_t)MR * C_ * 2;
    unsigned short* qb    = (unsigned short*)ws;                 ws += (size_t)MR * C_ * 2;
    unsigned short* kvb   = (unsigned short*)ws;                 ws += (size_t)MR * 512 * 2;
    unsigned short* attnb = (unsigned short*)ws;                 ws += (size_t)MR * C_ * 2;
    unsigned short* Wb    = (unsigned short*)ws;                 ws += (size_t)4 * C_ * C_ * 2;
    int* count       = (int*)ws;                                 ws += S_ * 4;
    int* base        = (int*)ws;                                 ws += (S_ + 1) * 4;
    int* cursor      = (int*)ws;                                 ws += S_ * 4;
    int* koff_sorted = (int*)ws;

    hipMemsetAsync(count, 0, S_ * sizeof(int), stream);
    prep_kernel<<<1664, 256, 0, stream>>>(q_id, count, x, xb, Wq, Wk, Wv, Wx, Wb);
    scan_kernel<<<1, 1024, 0, stream>>>(count, base, cursor);
    scatter_qkv_kernel<<<1024, 256, 0, stream>>>(q_id, k_id, cursor, koff_sorted,
                                                 xb, Wb, bq, bk, bv, qb, kvb);
    attn_edge<<<S_ / 2, 256, 0, stream>>>(qb, kvb, base, koff_sorted, attnb);
    gemm_proj<<<512, 256, 0, stream>>>(attnb, Wb + (size_t)3 * C_ * C_, bx, out);
}